// Round 1
// baseline (10256.009 us; speedup 1.0000x reference)
//
#include <hip/hip_runtime.h>
#include <hip/hip_bf16.h>

#define VSZ 1024   // vocab
#define HD  512    // hidden
#define NB  64     // batch
#define LQ  512    // seq len
#define G4  2048   // 4*H

__device__ __forceinline__ float bf2f(unsigned int u16) {
  unsigned int x = u16 << 16;
  float f;
  __builtin_memcpy(&f, &x, 4);
  return f;
}

// ---------------------------------------------------------------------------
// K1: G[v][new_j] = dot(emb[v,:], W_ih[old_j,:]) + b_ih[old_j] + b_hh[old_j]
//     new_j = h_idx*4 + gate ; old_j = gate*512 + h_idx  (gate-interleaved)
// 64x64 tile, K-chunk 32, 256 threads, 4x4 per thread. fp32.
// ---------------------------------------------------------------------------
__global__ __launch_bounds__(256)
void k_gtable(const float* __restrict__ emb, const float* __restrict__ Wih,
              const float* __restrict__ bih, const float* __restrict__ bhh,
              float* __restrict__ G)
{
  __shared__ float As[32][68];   // [k][v_local], stride 68 => 16B aligned rows
  __shared__ float Bs[32][68];   // [k][j_local]
  const int tid = threadIdx.x;
  const int tx = tid & 15, ty = tid >> 4;
  const int jn0 = blockIdx.x * 64;
  const int v0  = blockIdx.y * 64;
  const int lrow = tid >> 2, lkq = tid & 3;
  const int jn_l = jn0 + lrow;
  const int oldj_l = (jn_l & 3) * 512 + (jn_l >> 2);
  float acc[4][4] = {};
  for (int kc = 0; kc < HD; kc += 32) {
    const float4 a0 = *(const float4*)&emb[(v0 + lrow) * HD + kc + lkq * 8];
    const float4 a1 = *(const float4*)&emb[(v0 + lrow) * HD + kc + lkq * 8 + 4];
    const float4 b0 = *(const float4*)&Wih[oldj_l * HD + kc + lkq * 8];
    const float4 b1 = *(const float4*)&Wih[oldj_l * HD + kc + lkq * 8 + 4];
    __syncthreads();
    As[lkq*8+0][lrow] = a0.x; As[lkq*8+1][lrow] = a0.y;
    As[lkq*8+2][lrow] = a0.z; As[lkq*8+3][lrow] = a0.w;
    As[lkq*8+4][lrow] = a1.x; As[lkq*8+5][lrow] = a1.y;
    As[lkq*8+6][lrow] = a1.z; As[lkq*8+7][lrow] = a1.w;
    Bs[lkq*8+0][lrow] = b0.x; Bs[lkq*8+1][lrow] = b0.y;
    Bs[lkq*8+2][lrow] = b0.z; Bs[lkq*8+3][lrow] = b0.w;
    Bs[lkq*8+4][lrow] = b1.x; Bs[lkq*8+5][lrow] = b1.y;
    Bs[lkq*8+6][lrow] = b1.z; Bs[lkq*8+7][lrow] = b1.w;
    __syncthreads();
#pragma unroll
    for (int kk = 0; kk < 32; ++kk) {
      const float4 av = *(const float4*)&As[kk][ty*4];
      const float4 bv = *(const float4*)&Bs[kk][tx*4];
      acc[0][0] += av.x*bv.x; acc[0][1] += av.x*bv.y; acc[0][2] += av.x*bv.z; acc[0][3] += av.x*bv.w;
      acc[1][0] += av.y*bv.x; acc[1][1] += av.y*bv.y; acc[1][2] += av.y*bv.z; acc[1][3] += av.y*bv.w;
      acc[2][0] += av.z*bv.x; acc[2][1] += av.z*bv.y; acc[2][2] += av.z*bv.z; acc[2][3] += av.z*bv.w;
      acc[3][0] += av.w*bv.x; acc[3][1] += av.w*bv.y; acc[3][2] += av.w*bv.z; acc[3][3] += av.w*bv.w;
    }
  }
  float bias[4];
#pragma unroll
  for (int b = 0; b < 4; ++b) {
    const int jn = jn0 + tx*4 + b;
    const int oj = (jn & 3) * 512 + (jn >> 2);
    bias[b] = bih[oj] + bhh[oj];
  }
#pragma unroll
  for (int a = 0; a < 4; ++a) {
    const float4 st = make_float4(acc[a][0] + bias[0], acc[a][1] + bias[1],
                                  acc[a][2] + bias[2], acc[a][3] + bias[3]);
    *(float4*)&G[(v0 + ty*4 + a) * G4 + jn0 + tx*4] = st;
  }
}

// ---------------------------------------------------------------------------
// K2: W_T[k][new_j] = W_hh[old_j][k]   (k-major, gate-interleaved columns)
// ---------------------------------------------------------------------------
__global__ __launch_bounds__(256)
void k_transpose(const float* __restrict__ Whh, float* __restrict__ WT)
{
  const int idx  = blockIdx.x * 256 + threadIdx.x;  // 2048*128 total
  const int oldj = idx >> 7;
  const int kq   = (idx & 127) * 4;
  const float4 w = *(const float4*)&Whh[oldj * HD + kq];
  const int jn = (oldj & 511) * 4 + (oldj >> 9);
  WT[(kq+0)*G4 + jn] = w.x;
  WT[(kq+1)*G4 + jn] = w.y;
  WT[(kq+2)*G4 + jn] = w.z;
  WT[(kq+3)*G4 + jn] = w.w;
}

// ---------------------------------------------------------------------------
// K3: h0 = encoder_hidden[0]; c = 0
// ---------------------------------------------------------------------------
__global__ __launch_bounds__(256)
void k_init(const float* __restrict__ ehid, float* __restrict__ h0,
            float* __restrict__ c)
{
  const int i = blockIdx.x * 256 + threadIdx.x;   // grid covers NB*HD exactly
  h0[i] = ehid[i];
  c[i]  = 0.f;
}

// ---------------------------------------------------------------------------
// K4: one LSTM step. grid (32 j-blocks, 8 sample-blocks), 256 threads.
// Thread: one gate row j (lane-coalesced W_T reads) x 2 samples (wave-uniform
// h reads -> s_load). Gates exchanged through LDS for the cell update.
// ---------------------------------------------------------------------------
__global__ __launch_bounds__(256)
void k_step(const float* __restrict__ G, const float* __restrict__ WT,
            const int* __restrict__ target, const float* __restrict__ h_src,
            float* __restrict__ h_dst, float* __restrict__ c,
            __hip_bfloat16* __restrict__ Hall, const int t)
{
  __shared__ float gl[64][9];   // [j_local][sample_local], pad 9 vs banks
  const int tid = threadIdx.x;
  const int jl  = tid & 63;
  const int wv  = __builtin_amdgcn_readfirstlane(tid >> 6);  // wave id 0..3
  const int jb  = blockIdx.x;   // 0..31 : h-chunk of 16 (=64 gate rows)
  const int sb  = blockIdx.y;   // 0..7  : 8 samples
  const int j   = jb * 64 + jl;
  const int s0  = sb * 8 + wv * 2;
  const int tok0 = (t == 0) ? 0 : target[s0 * LQ + t - 1];
  const int tok1 = (t == 0) ? 0 : target[(s0 + 1) * LQ + t - 1];
  float acc0a = G[tok0 * G4 + j], acc0b = 0.f;
  float acc1a = G[tok1 * G4 + j], acc1b = 0.f;
  const float* hp0 = h_src + s0 * HD;
  const float* hp1 = hp0 + HD;
  for (int k = 0; k < HD; k += 8) {
    const float w0 = WT[(k+0)*G4 + j];
    const float w1 = WT[(k+1)*G4 + j];
    const float w2 = WT[(k+2)*G4 + j];
    const float w3 = WT[(k+3)*G4 + j];
    const float w4 = WT[(k+4)*G4 + j];
    const float w5 = WT[(k+5)*G4 + j];
    const float w6 = WT[(k+6)*G4 + j];
    const float w7 = WT[(k+7)*G4 + j];
    const float4 h0a = *(const float4*)(hp0 + k);
    const float4 h0b = *(const float4*)(hp0 + k + 4);
    const float4 h1a = *(const float4*)(hp1 + k);
    const float4 h1b = *(const float4*)(hp1 + k + 4);
    acc0a += w0*h0a.x; acc0b += w1*h0a.y; acc0a += w2*h0a.z; acc0b += w3*h0a.w;
    acc0a += w4*h0b.x; acc0b += w5*h0b.y; acc0a += w6*h0b.z; acc0b += w7*h0b.w;
    acc1a += w0*h1a.x; acc1b += w1*h1a.y; acc1a += w2*h1a.z; acc1b += w3*h1a.w;
    acc1a += w4*h1b.x; acc1b += w5*h1b.y; acc1a += w6*h1b.z; acc1b += w7*h1b.w;
  }
  gl[jl][wv*2+0] = acc0a + acc0b;
  gl[jl][wv*2+1] = acc1a + acc1b;
  __syncthreads();
  if (tid < 128) {
    const int hl = tid & 15;        // h index within chunk
    const int sl = tid >> 4;        // sample 0..7
    const float gi = gl[hl*4+0][sl];
    const float gf = gl[hl*4+1][sl];
    const float gg = gl[hl*4+2][sl];
    const float go = gl[hl*4+3][sl];
    const int n  = sb * 8 + sl;
    const int ci = n * HD + jb * 16 + hl;
    const float si = 1.f / (1.f + expf(-gi));
    const float sf = 1.f / (1.f + expf(-gf));
    const float tg = tanhf(gg);
    const float so = 1.f / (1.f + expf(-go));
    const float cn = sf * c[ci] + si * tg;
    const float hn = so * tanhf(cn);
    c[ci]     = cn;
    h_dst[ci] = hn;
    Hall[(t * NB + n) * HD + jb * 16 + hl] = __float2bfloat16(hn);
  }
}

// ---------------------------------------------------------------------------
// K5: copy final hidden state to output tail
// ---------------------------------------------------------------------------
__global__ __launch_bounds__(256)
void k_hout(const float* __restrict__ h, float* __restrict__ out)
{
  const int i = blockIdx.x * 256 + threadIdx.x;
  out[i] = h[i];
}

// ---------------------------------------------------------------------------
// K6: y[r][v] = dot(Hall_bf16[r,:], fc_W[v,:]) + fc_b[v]
// 64x64 tile, K-chunk 32, 256 threads, 4x4 per thread. fp32 accumulate.
// ---------------------------------------------------------------------------
__global__ __launch_bounds__(256)
void k_fc(const __hip_bfloat16* __restrict__ Hall, const float* __restrict__ fcW,
          const float* __restrict__ fcb, float* __restrict__ out)
{
  __shared__ float As[32][68];
  __shared__ float Bs[32][68];
  const int tid = threadIdx.x;
  const int tx = tid & 15, ty = tid >> 4;
  const int v0 = blockIdx.x * 64;
  const int r0 = blockIdx.y * 64;
  const int lrow = tid >> 2, lkq = tid & 3;
  const unsigned short* Hs = (const unsigned short*)Hall;
  float acc[4][4] = {};
  for (int kc = 0; kc < HD; kc += 32) {
    const uint4  ar = *(const uint4*)&Hs[(r0 + lrow) * HD + kc + lkq * 8];
    const float4 b0 = *(const float4*)&fcW[(v0 + lrow) * HD + kc + lkq * 8];
    const float4 b1 = *(const float4*)&fcW[(v0 + lrow) * HD + kc + lkq * 8 + 4];
    __syncthreads();
    As[lkq*8+0][lrow] = bf2f(ar.x & 0xffffu);
    As[lkq*8+1][lrow] = bf2f(ar.x >> 16);
    As[lkq*8+2][lrow] = bf2f(ar.y & 0xffffu);
    As[lkq*8+3][lrow] = bf2f(ar.y >> 16);
    As[lkq*8+4][lrow] = bf2f(ar.z & 0xffffu);
    As[lkq*8+5][lrow] = bf2f(ar.z >> 16);
    As[lkq*8+6][lrow] = bf2f(ar.w & 0xffffu);
    As[lkq*8+7][lrow] = bf2f(ar.w >> 16);
    Bs[lkq*8+0][lrow] = b0.x; Bs[lkq*8+1][lrow] = b0.y;
    Bs[lkq*8+2][lrow] = b0.z; Bs[lkq*8+3][lrow] = b0.w;
    Bs[lkq*8+4][lrow] = b1.x; Bs[lkq*8+5][lrow] = b1.y;
    Bs[lkq*8+6][lrow] = b1.z; Bs[lkq*8+7][lrow] = b1.w;
    __syncthreads();
#pragma unroll
    for (int kk = 0; kk < 32; ++kk) {
      const float4 av = *(const float4*)&As[kk][ty*4];
      const float4 bv = *(const float4*)&Bs[kk][tx*4];
      acc[0][0] += av.x*bv.x; acc[0][1] += av.x*bv.y; acc[0][2] += av.x*bv.z; acc[0][3] += av.x*bv.w;
      acc[1][0] += av.y*bv.x; acc[1][1] += av.y*bv.y; acc[1][2] += av.y*bv.z; acc[1][3] += av.y*bv.w;
      acc[2][0] += av.z*bv.x; acc[2][1] += av.z*bv.y; acc[2][2] += av.z*bv.z; acc[2][3] += av.z*bv.w;
      acc[3][0] += av.w*bv.x; acc[3][1] += av.w*bv.y; acc[3][2] += av.w*bv.z; acc[3][3] += av.w*bv.w;
    }
  }
  const int vb = v0 + tx * 4;
  const float4 bias = *(const float4*)&fcb[vb];
#pragma unroll
  for (int a = 0; a < 4; ++a) {
    const int r = r0 + ty * 4 + a;
    const float4 st = make_float4(acc[a][0] + bias.x, acc[a][1] + bias.y,
                                  acc[a][2] + bias.z, acc[a][3] + bias.w);
    *(float4*)&out[r * VSZ + vb] = st;
  }
}

// ---------------------------------------------------------------------------
extern "C" void kernel_launch(void* const* d_in, const int* in_sizes, int n_in,
                              void* d_out, int out_size, void* d_ws, size_t ws_size,
                              hipStream_t stream)
{
  (void)in_sizes; (void)n_in; (void)out_size; (void)ws_size;
  const float* enc_hid = (const float*)d_in[1];   // (1,64,512)
  const int*   target  = (const int*)  d_in[2];   // (64,512)
  const float* emb     = (const float*)d_in[3];   // (1024,512)
  const float* Wih     = (const float*)d_in[4];   // (2048,512)
  const float* Whh     = (const float*)d_in[5];   // (2048,512)
  const float* bih     = (const float*)d_in[6];   // (2048,)
  const float* bhh     = (const float*)d_in[7];   // (2048,)
  const float* fcW     = (const float*)d_in[8];   // (1024,512)
  const float* fcb     = (const float*)d_in[9];   // (1024,)
  float* out = (float*)d_out;

  char* ws = (char*)d_ws;
  float* G  = (float*)ws;                                   // 8 MB
  float* WT = (float*)(ws + (8u << 20));                    // 4 MB
  float* hbuf = (float*)(ws + (12u << 20));                 // 256 KB (ping-pong)
  float* c    = (float*)(ws + (12u << 20) + (256u << 10));  // 128 KB
  __hip_bfloat16* Hall =
      (__hip_bfloat16*)(ws + (12u << 20) + (384u << 10));   // 32 MB

  k_gtable<<<dim3(G4/64, VSZ/64), dim3(256), 0, stream>>>(emb, Wih, bih, bhh, G);
  k_transpose<<<dim3((G4*HD/4)/256), dim3(256), 0, stream>>>(Whh, WT);
  k_init<<<dim3((NB*HD)/256), dim3(256), 0, stream>>>(enc_hid, hbuf, c);

  for (int t = 0; t < LQ; ++t) {
    const float* hs = hbuf + (t & 1) * (NB * HD);
    float*       hd = hbuf + ((t + 1) & 1) * (NB * HD);
    k_step<<<dim3(32, 8), dim3(256), 0, stream>>>(G, WT, target, hs, hd, c, Hall, t);
  }

  k_hout<<<dim3((NB*HD)/256), dim3(256), 0, stream>>>(hbuf, out + (size_t)LQ*NB*VSZ);
  k_fc<<<dim3(VSZ/64, (LQ*NB)/64), dim3(256), 0, stream>>>(Hall, fcW, fcb, out);
}

// Round 2
// 5717.465 us; speedup vs baseline: 1.7938x; 1.7938x over previous
//
#include <hip/hip_runtime.h>
#include <hip/hip_bf16.h>

#define VSZ 1024   // vocab
#define HD  512    // hidden
#define NB  64     // batch
#define LQ  512    // seq len
#define G4  2048   // 4*H
#define NBLK 256   // persistent blocks (1 per CU)
#define HBUF 32768 // floats per h buffer (k-major: [256 k2][128 s*2+p])

__device__ __forceinline__ float bf2f(unsigned int u16) {
  unsigned int x = u16 << 16;
  float f;
  __builtin_memcpy(&f, &x, 4);
  return f;
}

#define GLOAD16(gp, lp) __builtin_amdgcn_global_load_lds( \
    (const __attribute__((address_space(1))) void*)(gp),  \
    (__attribute__((address_space(3))) void*)(lp), 16, 0, 0)

// ---------------------------------------------------------------------------
// K1: G[v][new_j] = dot(emb[v,:], W_ih[old_j,:]) + b_ih[old_j] + b_hh[old_j]
//     new_j = h_idx*4 + gate ; old_j = gate*512 + h_idx  (gate-interleaved)
// ---------------------------------------------------------------------------
__global__ __launch_bounds__(256)
void k_gtable(const float* __restrict__ emb, const float* __restrict__ Wih,
              const float* __restrict__ bih, const float* __restrict__ bhh,
              float* __restrict__ G)
{
  __shared__ float As[32][68];
  __shared__ float Bs[32][68];
  const int tid = threadIdx.x;
  const int tx = tid & 15, ty = tid >> 4;
  const int jn0 = blockIdx.x * 64;
  const int v0  = blockIdx.y * 64;
  const int lrow = tid >> 2, lkq = tid & 3;
  const int jn_l = jn0 + lrow;
  const int oldj_l = (jn_l & 3) * 512 + (jn_l >> 2);
  float acc[4][4] = {};
  for (int kc = 0; kc < HD; kc += 32) {
    const float4 a0 = *(const float4*)&emb[(v0 + lrow) * HD + kc + lkq * 8];
    const float4 a1 = *(const float4*)&emb[(v0 + lrow) * HD + kc + lkq * 8 + 4];
    const float4 b0 = *(const float4*)&Wih[oldj_l * HD + kc + lkq * 8];
    const float4 b1 = *(const float4*)&Wih[oldj_l * HD + kc + lkq * 8 + 4];
    __syncthreads();
    As[lkq*8+0][lrow] = a0.x; As[lkq*8+1][lrow] = a0.y;
    As[lkq*8+2][lrow] = a0.z; As[lkq*8+3][lrow] = a0.w;
    As[lkq*8+4][lrow] = a1.x; As[lkq*8+5][lrow] = a1.y;
    As[lkq*8+6][lrow] = a1.z; As[lkq*8+7][lrow] = a1.w;
    Bs[lkq*8+0][lrow] = b0.x; Bs[lkq*8+1][lrow] = b0.y;
    Bs[lkq*8+2][lrow] = b0.z; Bs[lkq*8+3][lrow] = b0.w;
    Bs[lkq*8+4][lrow] = b1.x; Bs[lkq*8+5][lrow] = b1.y;
    Bs[lkq*8+6][lrow] = b1.z; Bs[lkq*8+7][lrow] = b1.w;
    __syncthreads();
#pragma unroll
    for (int kk = 0; kk < 32; ++kk) {
      const float4 av = *(const float4*)&As[kk][ty*4];
      const float4 bv = *(const float4*)&Bs[kk][tx*4];
      acc[0][0] += av.x*bv.x; acc[0][1] += av.x*bv.y; acc[0][2] += av.x*bv.z; acc[0][3] += av.x*bv.w;
      acc[1][0] += av.y*bv.x; acc[1][1] += av.y*bv.y; acc[1][2] += av.y*bv.z; acc[1][3] += av.y*bv.w;
      acc[2][0] += av.z*bv.x; acc[2][1] += av.z*bv.y; acc[2][2] += av.z*bv.z; acc[2][3] += av.z*bv.w;
      acc[3][0] += av.w*bv.x; acc[3][1] += av.w*bv.y; acc[3][2] += av.w*bv.z; acc[3][3] += av.w*bv.w;
    }
  }
  float bias[4];
#pragma unroll
  for (int b = 0; b < 4; ++b) {
    const int jn = jn0 + tx*4 + b;
    const int oj = (jn & 3) * 512 + (jn >> 2);
    bias[b] = bih[oj] + bhh[oj];
  }
#pragma unroll
  for (int a = 0; a < 4; ++a) {
    const float4 st = make_float4(acc[a][0] + bias[0], acc[a][1] + bias[1],
                                  acc[a][2] + bias[2], acc[a][3] + bias[3]);
    *(float4*)&G[(v0 + ty*4 + a) * G4 + jn0 + tx*4] = st;
  }
}

// ---------------------------------------------------------------------------
// K2: init h buffer 0 (k-major layout) from encoder_hidden, zero sync counters
// ---------------------------------------------------------------------------
__global__ __launch_bounds__(256)
void k_init(const float* __restrict__ ehid, float* __restrict__ hbuf,
            int* __restrict__ cnt)
{
  const int i = blockIdx.x * 256 + threadIdx.x;
  if (i < NB * HD) {
    const int n = i >> 9, k = i & 511;
    hbuf[(k >> 1) * 128 + n * 2 + (k & 1)] = ehid[i];
  } else {
    const int j = i - NB * HD;
    if (j < 8 * LQ + LQ) cnt[j] = 0;   // cntA[8*512] then cntB[512]
  }
}

// ---------------------------------------------------------------------------
// K3: persistent LSTM. 256 blocks x 256 threads, one block per CU (forced by
// ~156KB LDS). Block b owns gate rows j=8b..8b+7 (h-units 2b,2b+1, all 4
// gates). W slice + c state stay in LDS for all 512 steps. Per step: stage
// h (k-major) via global_load_lds with progressive vmcnt gating; split-k
// (8 groups of 64 k) compute; shfl+LDS reduce; 128 threads do the cell
// update; h written with agent-scope stores; 2-level arrival counters + poll.
// ---------------------------------------------------------------------------
__global__ __launch_bounds__(256, 1)
void k_lstm(const float* __restrict__ G, const float* __restrict__ Whh,
            const int* __restrict__ target, float* __restrict__ hbuf,
            int* __restrict__ cntA, int* __restrict__ cntB,
            __hip_bfloat16* __restrict__ Hall)
{
  __shared__ float h_lds[256 * 128];   // 128 KB: [k2][s*2+p]
  __shared__ float W_lds[8][512];      // 16 KB
  __shared__ float part[4 * 32 * 16];  // 8 KB: [wave][s2][p*8 + r]
  __shared__ float g_pre[2 * 64 * 8];  // 4 KB: [parity][s][r]
  __shared__ float c_lds[128];         // [s*2+hu]

  const int tid = threadIdx.x;
  const int b   = blockIdx.x;
  const int s2  = tid & 31;       // sample pair index
  const int kq  = tid >> 5;       // k-quarter 0..7 (64 k each)
  const int w   = tid >> 6;       // wave 0..3
  const int kb  = kq * 64;
  const int k2b = kq * 32;
  const int grp = b & 7;

  // --- load W slice: row r = hu*4+g  ->  old_j = (r&3)*512 + 2b + (r>>2)
  {
    const int r = tid >> 5, cc = tid & 31;
    const int oldj = (r & 3) * 512 + 2 * b + (r >> 2);
    const float4* src = (const float4*)&Whh[(size_t)oldj * HD + cc * 16];
    float4* dst = (float4*)&W_lds[r][cc * 16];
    dst[0] = src[0]; dst[1] = src[1]; dst[2] = src[2]; dst[3] = src[3];
  }
  if (tid < 128) c_lds[tid] = 0.f;
  if (tid < 64) {  // g_pre for t=0: token 0 for every sample
    const float4 g0 = *(const float4*)&G[(size_t)0 * G4 + b * 8];
    const float4 g1 = *(const float4*)&G[(size_t)0 * G4 + b * 8 + 4];
    *(float4*)&g_pre[tid * 8]     = g0;
    *(float4*)&g_pre[tid * 8 + 4] = g1;
  }
  __syncthreads();

  int dead = 0;
  for (int t = 0; t < LQ; ++t) {
    // ---- wait for h(t) ready (t=0: stream-ordered k_init)
    if (t > 0) {
      if (tid == 0) {
        if (!dead) {
          int it = 0;
          while (__hip_atomic_load(&cntB[t - 1], __ATOMIC_RELAXED,
                                   __HIP_MEMORY_SCOPE_AGENT) < 8) {
            __builtin_amdgcn_s_sleep(2);
            if (++it > (1 << 19)) { dead = 1; break; }
          }
        }
        __builtin_amdgcn_fence(__ATOMIC_ACQUIRE, "agent");
      }
      __syncthreads();
    }

    // ---- stage this wave's h slab (32 KB = 32 x 1KB gload_lds)
    {
      const float* hsrc = hbuf + (size_t)(t & 1) * HBUF + w * 8192 + (tid & 63) * 4;
      float* lb = &h_lds[w * 8192];
#pragma unroll
      for (int i = 0; i < 32; ++i)
        GLOAD16(hsrc + i * 256, lb + i * 256);
    }

    // ---- split-k compute: thread (s2, kq): samples {2s2,2s2+1} x rows 0..7
    float accA[8] = {}, accB[8] = {};
#define CHUNK(c, VM) {                                                        \
    asm volatile("s_waitcnt vmcnt(" #VM ")" ::: "memory");                    \
    const float4 hA = *(const float4*)&h_lds[(k2b + 2*(c)) * 128 + s2 * 4];   \
    const float4 hB = *(const float4*)&h_lds[(k2b + 2*(c) + 1) * 128 + s2 * 4];\
    _Pragma("unroll")                                                         \
    for (int r = 0; r < 8; ++r) {                                             \
      const float4 wv = *(const float4*)&W_lds[r][kb + 4*(c)];                \
      accA[r] += wv.x*hA.x + wv.y*hA.y + wv.z*hB.x + wv.w*hB.y;               \
      accB[r] += wv.x*hA.z + wv.y*hA.w + wv.z*hB.z + wv.w*hB.w;               \
    } }
    CHUNK(0,15)  CHUNK(1,14)  CHUNK(2,13)  CHUNK(3,12)
    CHUNK(4,11)  CHUNK(5,10)  CHUNK(6,9)   CHUNK(7,8)
    CHUNK(8,7)   CHUNK(9,6)   CHUNK(10,5)  CHUNK(11,4)
    CHUNK(12,3)  CHUNK(13,2)  CHUNK(14,1)  CHUNK(15,0)
#undef CHUNK

    // ---- reduce kq pairs in-wave, park wave partials in LDS
#pragma unroll
    for (int r = 0; r < 8; ++r) {
      accA[r] += __shfl_xor(accA[r], 32, 64);
      accB[r] += __shfl_xor(accB[r], 32, 64);
    }
    if ((tid & 32) == 0) {
      float* pp = &part[w * 512 + s2 * 16];
#pragma unroll
      for (int r = 0; r < 8; ++r) { pp[r] = accA[r]; pp[8 + r] = accB[r]; }
    }

    // ---- prefetch G rows for step t+1 (tokens independent of h)
    float4 gp0, gp1;
    int havep = 0;
    if (tid < 64 && t + 1 < LQ) {
      const int tok = target[(size_t)tid * LQ + t];   // tokens for step t+1
      gp0 = *(const float4*)&G[(size_t)tok * G4 + b * 8];
      gp1 = *(const float4*)&G[(size_t)tok * G4 + b * 8 + 4];
      havep = 1;
    }
    __syncthreads();   // B1: partials visible

    // ---- cell update: 128 threads, tid = s*2 + hu
    if (tid < 128) {
      const int hu = tid & 1, s = tid >> 1;
      const int s2u = s >> 1, p = s & 1;
      const float* pp = &part[s2u * 16 + p * 8 + hu * 4];
      const float* gg = &g_pre[(t & 1) * 512 + s * 8 + hu * 4];
      const float vi = gg[0] + pp[0] + pp[512] + pp[1024] + pp[1536];
      const float vf = gg[1] + pp[1] + pp[513] + pp[1025] + pp[1537];
      const float vg = gg[2] + pp[2] + pp[514] + pp[1026] + pp[1538];
      const float vo = gg[3] + pp[3] + pp[515] + pp[1027] + pp[1539];
      const float si = 1.f / (1.f + expf(-vi));
      const float sf = 1.f / (1.f + expf(-vf));
      const float tg = tanhf(vg);
      const float so = 1.f / (1.f + expf(-vo));
      const float cn = sf * c_lds[tid] + si * tg;
      const float hn = so * tanhf(cn);
      c_lds[tid] = cn;
      __hip_atomic_store(&hbuf[(size_t)((t + 1) & 1) * HBUF + b * 128 + tid],
                         hn, __ATOMIC_RELAXED, __HIP_MEMORY_SCOPE_AGENT);
      Hall[((size_t)t * NB + s) * HD + 2 * b + hu] = __float2bfloat16(hn);
    }
    if (havep) {
      *(float4*)&g_pre[((t + 1) & 1) * 512 + tid * 8]     = gp0;
      *(float4*)&g_pre[((t + 1) & 1) * 512 + tid * 8 + 4] = gp1;
    }
    __syncthreads();   // B2: drains h stores (vmcnt(0)) before arrival

    // ---- 2-level arrival: 32 blocks per group line, then top line
    if (tid == 0) {
      const int a = __hip_atomic_fetch_add(&cntA[grp * LQ + t], 1,
                      __ATOMIC_RELAXED, __HIP_MEMORY_SCOPE_AGENT);
      if (a == 31)
        __hip_atomic_fetch_add(&cntB[t], 1,
                      __ATOMIC_RELAXED, __HIP_MEMORY_SCOPE_AGENT);
    }
  }
}

// ---------------------------------------------------------------------------
// K4: final hidden state (k-major buffer 0) -> output tail [n][k]
// ---------------------------------------------------------------------------
__global__ __launch_bounds__(256)
void k_hout(const float* __restrict__ hb0, float* __restrict__ out)
{
  const int i = blockIdx.x * 256 + threadIdx.x;
  const int n = i >> 9, k = i & 511;
  out[i] = hb0[(k >> 1) * 128 + n * 2 + (k & 1)];
}

// ---------------------------------------------------------------------------
// K5: y[r][v] = dot(Hall_bf16[r,:], fc_W[v,:]) + fc_b[v]
// ---------------------------------------------------------------------------
__global__ __launch_bounds__(256)
void k_fc(const __hip_bfloat16* __restrict__ Hall, const float* __restrict__ fcW,
          const float* __restrict__ fcb, float* __restrict__ out)
{
  __shared__ float As[32][68];
  __shared__ float Bs[32][68];
  const int tid = threadIdx.x;
  const int tx = tid & 15, ty = tid >> 4;
  const int v0 = blockIdx.x * 64;
  const int r0 = blockIdx.y * 64;
  const int lrow = tid >> 2, lkq = tid & 3;
  const unsigned short* Hs = (const unsigned short*)Hall;
  float acc[4][4] = {};
  for (int kc = 0; kc < HD; kc += 32) {
    const uint4  ar = *(const uint4*)&Hs[(size_t)(r0 + lrow) * HD + kc + lkq * 8];
    const float4 b0 = *(const float4*)&fcW[(v0 + lrow) * HD + kc + lkq * 8];
    const float4 b1 = *(const float4*)&fcW[(v0 + lrow) * HD + kc + lkq * 8 + 4];
    __syncthreads();
    As[lkq*8+0][lrow] = bf2f(ar.x & 0xffffu);
    As[lkq*8+1][lrow] = bf2f(ar.x >> 16);
    As[lkq*8+2][lrow] = bf2f(ar.y & 0xffffu);
    As[lkq*8+3][lrow] = bf2f(ar.y >> 16);
    As[lkq*8+4][lrow] = bf2f(ar.z & 0xffffu);
    As[lkq*8+5][lrow] = bf2f(ar.z >> 16);
    As[lkq*8+6][lrow] = bf2f(ar.w & 0xffffu);
    As[lkq*8+7][lrow] = bf2f(ar.w >> 16);
    Bs[lkq*8+0][lrow] = b0.x; Bs[lkq*8+1][lrow] = b0.y;
    Bs[lkq*8+2][lrow] = b0.z; Bs[lkq*8+3][lrow] = b0.w;
    Bs[lkq*8+4][lrow] = b1.x; Bs[lkq*8+5][lrow] = b1.y;
    Bs[lkq*8+6][lrow] = b1.z; Bs[lkq*8+7][lrow] = b1.w;
    __syncthreads();
#pragma unroll
    for (int kk = 0; kk < 32; ++kk) {
      const float4 av = *(const float4*)&As[kk][ty*4];
      const float4 bv = *(const float4*)&Bs[kk][tx*4];
      acc[0][0] += av.x*bv.x; acc[0][1] += av.x*bv.y; acc[0][2] += av.x*bv.z; acc[0][3] += av.x*bv.w;
      acc[1][0] += av.y*bv.x; acc[1][1] += av.y*bv.y; acc[1][2] += av.y*bv.z; acc[1][3] += av.y*bv.w;
      acc[2][0] += av.z*bv.x; acc[2][1] += av.z*bv.y; acc[2][2] += av.z*bv.z; acc[2][3] += av.z*bv.w;
      acc[3][0] += av.w*bv.x; acc[3][1] += av.w*bv.y; acc[3][2] += av.w*bv.z; acc[3][3] += av.w*bv.w;
    }
  }
  const int vb = v0 + tx * 4;
  const float4 bias = *(const float4*)&fcb[vb];
#pragma unroll
  for (int a = 0; a < 4; ++a) {
    const int r = r0 + ty * 4 + a;
    const float4 st = make_float4(acc[a][0] + bias.x, acc[a][1] + bias.y,
                                  acc[a][2] + bias.z, acc[a][3] + bias.w);
    *(float4*)&out[(size_t)r * VSZ + vb] = st;
  }
}

// ---------------------------------------------------------------------------
extern "C" void kernel_launch(void* const* d_in, const int* in_sizes, int n_in,
                              void* d_out, int out_size, void* d_ws, size_t ws_size,
                              hipStream_t stream)
{
  (void)in_sizes; (void)n_in; (void)out_size; (void)ws_size;
  const float* enc_hid = (const float*)d_in[1];   // (1,64,512)
  const int*   target  = (const int*)  d_in[2];   // (64,512)
  const float* emb     = (const float*)d_in[3];   // (1024,512)
  const float* Wih     = (const float*)d_in[4];   // (2048,512)
  const float* Whh     = (const float*)d_in[5];   // (2048,512)
  const float* bih     = (const float*)d_in[6];   // (2048,)
  const float* bhh     = (const float*)d_in[7];   // (2048,)
  const float* fcW     = (const float*)d_in[8];   // (1024,512)
  const float* fcb     = (const float*)d_in[9];   // (1024,)
  float* out = (float*)d_out;

  char* ws = (char*)d_ws;
  float* G  = (float*)ws;                                   // 8 MB
  __hip_bfloat16* Hall = (__hip_bfloat16*)(ws + (8u << 20)); // 32 MB
  float* hbuf = (float*)(ws + (40u << 20));                 // 2 x 128 KB
  int*   cnt  = (int*)(ws + (40u << 20) + (512u << 10));    // 4608 ints
  int*   cntA = cnt;
  int*   cntB = cnt + 8 * LQ;

  k_gtable<<<dim3(G4/64, VSZ/64), dim3(256), 0, stream>>>(emb, Wih, bih, bhh, G);
  k_init<<<dim3(146), dim3(256), 0, stream>>>(enc_hid, hbuf, cnt);
  k_lstm<<<dim3(NBLK), dim3(256), 0, stream>>>(G, Whh, target, hbuf, cntA, cntB, Hall);
  k_hout<<<dim3((NB*HD)/256), dim3(256), 0, stream>>>(hbuf, out + (size_t)LQ*NB*VSZ);
  k_fc<<<dim3(VSZ/64, (LQ*NB)/64), dim3(256), 0, stream>>>(Hall, fcW, fcb, out);
}